// Round 1
// baseline (1456.822 us; speedup 1.0000x reference)
//
#include <hip/hip_runtime.h>
#include <hip/hip_bf16.h>

#define B_SZ   8192
#define F_CNT  16
#define E_DIM  32
#define V_CNT  100000
#define D_CNT  8
#define H1     1024
#define H2     512
#define IN_DIM 512
#define EPS_BN 1e-5f

typedef __attribute__((ext_vector_type(8))) unsigned short ushort8;
typedef __attribute__((ext_vector_type(8))) short          frag_ab;
typedef __attribute__((ext_vector_type(4))) float          frag_cd;
typedef __attribute__((ext_vector_type(4))) float          float4v;

__device__ inline unsigned short f2b(float f) {
    unsigned int u = __builtin_bit_cast(unsigned int, f);
    unsigned int r = u + 0x7FFFu + ((u >> 16) & 1u);   // RNE
    return (unsigned short)(r >> 16);
}
__device__ inline float b2f(unsigned short b) {
    return __builtin_bit_cast(float, (unsigned int)b << 16);
}

// async global->LDS DMA, 16B per lane; LDS dest = wave-uniform base + lane*16
__device__ inline void ld_lds16(const unsigned short* g, unsigned short* l) {
    __builtin_amdgcn_global_load_lds(
        (const __attribute__((address_space(1))) unsigned int*)g,
        (__attribute__((address_space(3))) unsigned int*)l, 16, 0, 0);
}

// ---- merged init: W1/W2/W3/b3 fp32->bf16 + zero stats/counters ---------------
// blocks [0,4096): W1 ; [4096,8192): W2 ; 8192: W3+b3 ; [8193,8218): zero 24672 f
__global__ void k_init(const float* __restrict__ W1, const float* __restrict__ W2,
                       const float* __restrict__ W3, const float* __restrict__ b3,
                       unsigned short* __restrict__ W1c, unsigned short* __restrict__ W2c,
                       unsigned short* __restrict__ W3c, unsigned short* __restrict__ b3c,
                       float* __restrict__ zb) {
    int bid = blockIdx.x, t = threadIdx.x;
    if (bid < 8192) {
        const float* src = (bid < 4096) ? W1 : W2;
        unsigned short* dst = (bid < 4096) ? W1c : W2c;
        long i = ((long)(bid & 4095) * 256 + t) * 4;
        float4v v = *(const float4v*)(src + i);
        dst[i]     = f2b(v[0]);
        dst[i + 1] = f2b(v[1]);
        dst[i + 2] = f2b(v[2]);
        dst[i + 3] = f2b(v[3]);
    } else if (bid == 8192) {
        const float* s = W3 + t * 16;
        unsigned short* d = W3c + t * 16;
#pragma unroll
        for (int j = 0; j < 4; j++) {
            float4v v = *(const float4v*)(s + j * 4);
            d[j * 4 + 0] = f2b(v[0]); d[j * 4 + 1] = f2b(v[1]);
            d[j * 4 + 2] = f2b(v[2]); d[j * 4 + 3] = f2b(v[3]);
        }
        if (t < D_CNT) b3c[t] = f2b(b3[t]);
    } else {
        int i = (bid - 8193) * 1024 + t * 4;
        if (i < 24672) *(float4v*)(zb + i) = (float4v){0.f, 0.f, 0.f, 0.f};
    }
}

// ---- embedding gather fp32 tables -> bf16 emb[b, f*32+e] ---------------------
__global__ void k_gather(const int* __restrict__ feat_ids,
                         const float* __restrict__ tables,
                         unsigned short* __restrict__ emb) {
    int tid = blockIdx.x * 256 + threadIdx.x;    // B*64 threads, 8-elem chunks
    int b = tid >> 6;
    int c = tid & 63;
    int f = c >> 2;
    int id = feat_ids[b * F_CNT + f];
    const float* s = tables + ((long)f * V_CNT + id) * E_DIM + (c & 3) * 8;
    float4v v0 = *(const float4v*)s;
    float4v v1 = *(const float4v*)(s + 4);
    ushort8 o;
#pragma unroll
    for (int i = 0; i < 4; i++) { o[i] = f2b(v0[i]); o[i + 4] = f2b(v1[i]); }
    *(ushort8*)(emb + (long)b * IN_DIM + c * 8) = o;
}

// ---- shared epilogue: bf16 C store + per-column sum/sumsq + last-block BN finalize
__device__ inline void gemm_epilogue(frag_cd acc[4][4],
                                     unsigned short* __restrict__ Cd,
                                     float* __restrict__ gsum, float* __restrict__ gsq,
                                     int* __restrict__ cnt,
                                     const float* __restrict__ g, const float* __restrict__ be,
                                     float* __restrict__ scale, float* __restrict__ shift,
                                     int N, int d, int m0, int n0,
                                     int wm, int wn, int q, int lr, int lane, int t) {
    float s[4], q2[4];
#pragma unroll
    for (int j = 0; j < 4; j++) { s[j] = 0.f; q2[j] = 0.f; }
#pragma unroll
    for (int i = 0; i < 4; i++) {
        int row = m0 + wm + i * 16 + q * 4;          // C/D: col=lane&15, row=quad*4+reg
#pragma unroll
        for (int j = 0; j < 4; j++) {
            int col = n0 + wn + j * 16 + lr;
#pragma unroll
            for (int r = 0; r < 4; r++) {
                float v = acc[i][j][r];
                Cd[(long)(row + r) * N + col] = f2b(v);
                s[j] += v; q2[j] += v * v;
            }
        }
    }
    // collapse the 4 q-quads (same col, different rows): lanes differ in bits 4,5
#pragma unroll
    for (int j = 0; j < 4; j++) {
        s[j]  += __shfl_xor(s[j], 16, 64);  s[j]  += __shfl_xor(s[j], 32, 64);
        q2[j] += __shfl_xor(q2[j], 16, 64); q2[j] += __shfl_xor(q2[j], 32, 64);
    }
    if (lane < 16) {
        float* gs = gsum + (long)d * N + n0 + wn;
        float* gq = gsq  + (long)d * N + n0 + wn;
#pragma unroll
        for (int j = 0; j < 4; j++) {
            atomicAdd(&gs[j * 16 + lane], s[j]);
            atomicAdd(&gq[j * 16 + lane], q2[j]);
        }
    }
    // split-K-style finalize: last x-block of this (d, n-strip) computes scale/shift
    __threadfence();                                 // release our stat atomics
    __shared__ int lastDone;
    if (t == 0) {
        int c = atomicAdd(&cnt[d * gridDim.y + blockIdx.y], 1);
        lastDone = (c == (int)gridDim.x - 1);
    }
    __syncthreads();
    if (lastDone && t < 128) {
        int col = n0 + t;
        // read stats at the coherent point (dodges stale L1 across XCDs)
        float sm = atomicAdd(&gsum[(long)d * N + col], 0.f);
        float sq = atomicAdd(&gsq [(long)d * N + col], 0.f);
        float mean = sm * (1.0f / B_SZ);
        float var  = sq * (1.0f / B_SZ) - mean * mean;
        float sc   = g[(long)d * N + col] * rsqrtf(var + EPS_BN);
        scale[(long)d * N + col] = sc;
        shift[(long)d * N + col] = be[(long)d * N + col] - mean * sc;
    }
}

// ---- Layer-1 GEMM: DMA-staged A (emb) & W; fused stats + in-kernel finalize --
__global__ __launch_bounds__(256, 2)
void k_gemm1(const unsigned short* __restrict__ A,
             const unsigned short* __restrict__ W,
             unsigned short* __restrict__ C,
             float* __restrict__ gsum, float* __restrict__ gsq, int* __restrict__ cnt,
             const float* __restrict__ g, const float* __restrict__ be,
             float* __restrict__ scale, float* __restrict__ shift,
             int M, int N, int K, long aBatchStride, int d0) {
    const int z  = blockIdx.z;
    const int m0 = blockIdx.x * 128;
    const int n0 = blockIdx.y * 128;
    const unsigned short* Ad = A + (long)z * aBatchStride;
    const unsigned short* Wd = W + (long)(d0 + z) * N * K;

    __shared__ unsigned short As[128 * 32];   // unpadded: required by global_load_lds
    __shared__ unsigned short Bs[128 * 32];

    const int t    = threadIdx.x;
    const int wave = t >> 6;
    const int lane = t & 63;
    const int wm   = (wave & 1) << 6;
    const int wn   = (wave >> 1) << 6;
    const int q    = lane >> 4;
    const int lr   = lane & 15;

    const int srow = lane >> 2;
    const int scol = (lane & 3) * 8;
    const unsigned short* aG0 = Ad + (long)(m0 + wave * 32 + srow) * K + scol;
    const unsigned short* aG1 = aG0 + 16 * (long)K;
    const unsigned short* wG0 = Wd + (long)(n0 + wave * 32 + srow) * K + scol;
    const unsigned short* wG1 = wG0 + 16 * (long)K;
    unsigned short* aL0 = &As[(wave * 32) * 32];       // wave-uniform
    unsigned short* aL1 = &As[(wave * 32 + 16) * 32];
    unsigned short* wL0 = &Bs[(wave * 32) * 32];
    unsigned short* wL1 = &Bs[(wave * 32 + 16) * 32];

    frag_cd acc[4][4];
#pragma unroll
    for (int i = 0; i < 4; i++)
#pragma unroll
        for (int j = 0; j < 4; j++)
            acc[i][j] = (frag_cd){0.f, 0.f, 0.f, 0.f};

    for (int k0 = 0; k0 < K; k0 += 32) {
        ld_lds16(aG0 + k0, aL0);
        ld_lds16(aG1 + k0, aL1);
        ld_lds16(wG0 + k0, wL0);
        ld_lds16(wG1 + k0, wL1);
        __syncthreads();                       // drains vmcnt before barrier

        frag_ab af[4], bf[4];
#pragma unroll
        for (int i = 0; i < 4; i++) {
            af[i] = *(const frag_ab*)&As[(wm + i * 16 + lr) * 32 + q * 8];
            bf[i] = *(const frag_ab*)&Bs[(wn + i * 16 + lr) * 32 + q * 8];
        }
#pragma unroll
        for (int i = 0; i < 4; i++)
#pragma unroll
            for (int j = 0; j < 4; j++)
                acc[i][j] = __builtin_amdgcn_mfma_f32_16x16x32_bf16(af[i], bf[j], acc[i][j], 0, 0, 0);
        __syncthreads();                       // LDS reads done before next DMA
    }

    unsigned short* Cd = C + (long)z * M * N;
    gemm_epilogue(acc, Cd, gsum, gsq, cnt, g, be, scale, shift,
                  N, d0 + z, m0, n0, wm, wn, q, lr, lane, t);
}

// ---- Layer-2 GEMM: reg-staged A with fused BN1(scale/shift)+ReLU; DMA W ------
__global__ __launch_bounds__(256, 2)
void k_gemm2(const unsigned short* __restrict__ A,
             const unsigned short* __restrict__ W,
             unsigned short* __restrict__ C,
             float* __restrict__ gsum, float* __restrict__ gsq, int* __restrict__ cnt,
             const float* __restrict__ g, const float* __restrict__ be,
             float* __restrict__ scale, float* __restrict__ shift,
             const float* __restrict__ sc1, const float* __restrict__ sh1,
             int M, int N, int K, long aBatchStride, int d0) {
    const int z  = blockIdx.z;
    const int m0 = blockIdx.x * 128;
    const int n0 = blockIdx.y * 128;
    const unsigned short* Ad = A + (long)z * aBatchStride;
    const unsigned short* Wd = W + (long)(d0 + z) * N * K;

    __shared__ unsigned short As[128 * 32];
    __shared__ unsigned short Bs[128 * 32];

    const int t    = threadIdx.x;
    const int wave = t >> 6;
    const int lane = t & 63;
    const int wm   = (wave & 1) << 6;
    const int wn   = (wave >> 1) << 6;
    const int q    = lane >> 4;
    const int lr   = lane & 15;

    const int srow = lane >> 2;
    const int scol = (lane & 3) * 8;
    // A reg-staged (BN1+ReLU applied en route); W via global_load_lds
    const unsigned short* aP0 = Ad + (long)(m0 + wave * 32 + srow) * K + scol;
    const unsigned short* aP1 = aP0 + 16 * (long)K;
    const float* scD = sc1 + (long)(d0 + z) * K;   // K == H1; scale/shift index = k
    const float* shD = sh1 + (long)(d0 + z) * K;
    const unsigned short* wG0 = Wd + (long)(n0 + wave * 32 + srow) * K + scol;
    const unsigned short* wG1 = wG0 + 16 * (long)K;
    unsigned short* aL0w = &As[(wave * 32 + srow) * 32 + scol];
    unsigned short* aL1w = aL0w + 16 * 32;
    unsigned short* wL0 = &Bs[(wave * 32) * 32];
    unsigned short* wL1 = &Bs[(wave * 32 + 16) * 32];

    frag_cd acc[4][4];
#pragma unroll
    for (int i = 0; i < 4; i++)
#pragma unroll
        for (int j = 0; j < 4; j++)
            acc[i][j] = (frag_cd){0.f, 0.f, 0.f, 0.f};

    ushort8 x0 = *(const ushort8*)aP0;             // prologue load (k0 = 0)
    ushort8 x1 = *(const ushort8*)aP1;

    for (int k0 = 0; k0 < K; k0 += 32) {
        ld_lds16(wG0 + k0, wL0);                   // W DMA in flight over transform
        ld_lds16(wG1 + k0, wL1);
        float4v sa = *(const float4v*)(scD + k0 + scol);
        float4v sb = *(const float4v*)(scD + k0 + scol + 4);
        float4v ha = *(const float4v*)(shD + k0 + scol);
        float4v hb = *(const float4v*)(shD + k0 + scol + 4);
        ushort8 y0, y1;
#pragma unroll
        for (int i2 = 0; i2 < 8; i2++) {
            float scv = (i2 < 4) ? sa[i2] : sb[i2 - 4];
            float shv = (i2 < 4) ? ha[i2] : hb[i2 - 4];
            y0[i2] = f2b(fmaxf(b2f(x0[i2]) * scv + shv, 0.f));
            y1[i2] = f2b(fmaxf(b2f(x1[i2]) * scv + shv, 0.f));
        }
        *(ushort8*)aL0w = y0;
        *(ushort8*)aL1w = y1;
        __syncthreads();                           // ds_write visible + W DMA drained

        if (k0 + 32 < K) {                         // early-issue next A chunk (T14-lite)
            x0 = *(const ushort8*)(aP0 + k0 + 32);
            x1 = *(const ushort8*)(aP1 + k0 + 32);
        }

        frag_ab af[4], bf[4];
#pragma unroll
        for (int i = 0; i < 4; i++) {
            af[i] = *(const frag_ab*)&As[(wm + i * 16 + lr) * 32 + q * 8];
            bf[i] = *(const frag_ab*)&Bs[(wn + i * 16 + lr) * 32 + q * 8];
        }
#pragma unroll
        for (int i = 0; i < 4; i++)
#pragma unroll
            for (int j = 0; j < 4; j++)
                acc[i][j] = __builtin_amdgcn_mfma_f32_16x16x32_bf16(af[i], bf[j], acc[i][j], 0, 0, 0);
        __syncthreads();
    }

    unsigned short* Cd = C + (long)z * M * N;
    gemm_epilogue(acc, Cd, gsum, gsq, cnt, g, be, scale, shift,
                  N, d0 + z, m0, n0, wm, wn, q, lr, lane, t);
}

// ---- fused BN2+ReLU+W3 dot+sigmoid+domain select (fp32 out) -------------------
__global__ void k_final(const unsigned short* __restrict__ h2c,
                        const int* __restrict__ domain_id,
                        const float* __restrict__ scale2, const float* __restrict__ shift2,
                        const unsigned short* __restrict__ W3, const unsigned short* __restrict__ b3,
                        float* __restrict__ out, int d0, int nc) {
    int wave = threadIdx.x >> 6, lane = threadIdx.x & 63;
    int b = blockIdx.x * 4 + wave;
    int d = domain_id[b];
    if (d < d0 || d >= d0 + nc) return;          // wave-uniform exit
    int o = d * H2 + lane * 8;
    ushort8 v = *(const ushort8*)(h2c + ((long)(d - d0) * B_SZ + b) * H2 + lane * 8);
    ushort8 w = *(const ushort8*)(W3 + o);
    float sum = 0.f;
#pragma unroll
    for (int i = 0; i < 8; i++) {
        float x = b2f(v[i]) * scale2[o + i] + shift2[o + i];
        sum += fmaxf(x, 0.f) * b2f(w[i]);
    }
#pragma unroll
    for (int off = 32; off > 0; off >>= 1) sum += __shfl_xor(sum, off, 64);
    if (lane == 0)
        out[b] = 1.f / (1.f + expf(-(sum + b2f(b3[d]))));
}

__global__ void k_sentinel(float* __restrict__ out, int n) {
    int i = blockIdx.x * 256 + threadIdx.x;
    if (i < n) out[i] = 0.25f;   // diagnostic: ws too small
}

extern "C" void kernel_launch(void* const* d_in, const int* in_sizes, int n_in,
                              void* d_out, int out_size, void* d_ws, size_t ws_size,
                              hipStream_t stream) {
    const int*   feat_ids  = (const int*)d_in[0];
    const int*   domain_id = (const int*)d_in[1];
    const float* tables = (const float*)d_in[2];
    const float* W1  = (const float*)d_in[3];
    // d_in[4] = b1: dead (BN subtracts batch mean)
    const float* g1  = (const float*)d_in[5];
    const float* be1 = (const float*)d_in[6];
    const float* W2  = (const float*)d_in[7];
    // d_in[8] = b2: dead
    const float* g2  = (const float*)d_in[9];
    const float* be2 = (const float*)d_in[10];
    const float* W3  = (const float*)d_in[11];
    const float* b3  = (const float*)d_in[12];

    char* ws = (char*)d_ws;
    float* gsum1  = (float*)ws;            // 8192
    float* gsq1   = gsum1 + 8192;          // 8192
    float* gsum2  = gsq1 + 8192;           // 4096
    float* gsq2   = gsum2 + 4096;          // 4096
    int*   cnt1   = (int*)(gsq2 + 4096);   // 64   (D * 8 n-strips)
    int*   cnt2   = cnt1 + 64;             // 32   (D * 4 n-strips)
    float* scale1 = (float*)(cnt2 + 32);   // 8192 (absolute [D][H1])
    float* shift1 = scale1 + 8192;         // 8192
    float* scale2 = shift1 + 8192;         // 4096 (absolute [D][H2])
    float* shift2 = scale2 + 4096;         // 4096
    unsigned short* W1c = (unsigned short*)(ws + (1L  << 20));
    unsigned short* W2c = (unsigned short*)(ws + (9L  << 20));
    unsigned short* W3c = (unsigned short*)(ws + (17L << 20));
    unsigned short* b3c = W3c + D_CNT * H2;
    unsigned short* emb = (unsigned short*)(ws + (18L << 20));

    const long h1Elems = (long)B_SZ * H1;
    const long h2Elems = (long)B_SZ * H2;
    const long perDom  = (h1Elems + h2Elems) * 2;
    const long baseOff = 26L << 20;
    int NC = 0;
    for (int cand = 8; cand >= 1; cand >>= 1)
        if (baseOff + (long)cand * perDom <= (long)ws_size) { NC = cand; break; }
    if (NC == 0) {
        k_sentinel<<<dim3((out_size + 255) / 256), dim3(256), 0, stream>>>(
            (float*)d_out, out_size);
        return;
    }
    unsigned short* h1c = (unsigned short*)(ws + baseOff);
    unsigned short* h2c = h1c + (long)NC * h1Elems;

    // merged: W1/W2/W3/b3 convert + zero(gsum/gsq/cnt = 24672 words)
    k_init<<<dim3(8218), dim3(256), 0, stream>>>(W1, W2, W3, b3, W1c, W2c, W3c, b3c, gsum1);
    k_gather<<<dim3(2048), dim3(256), 0, stream>>>(feat_ids, tables, emb);

    for (int d0 = 0; d0 < D_CNT; d0 += NC) {
        // Layer 1: M=8192,N=1024,K=512 ; A=emb shared (stride 0); stats+finalize fused
        k_gemm1<<<dim3(64, 8, NC), dim3(256), 0, stream>>>(
            emb, W1c, h1c, gsum1, gsq1, cnt1, g1, be1, scale1, shift1,
            8192, 1024, 512, 0L, d0);
        // Layer 2: M=8192,N=512,K=1024 ; A=h1c (pre-BN) with fused BN1+ReLU staging
        k_gemm2<<<dim3(64, 4, NC), dim3(256), 0, stream>>>(
            h1c, W2c, h2c, gsum2, gsq2, cnt2, g2, be2, scale2, shift2,
            scale1, shift1, 8192, 512, 1024, h1Elems, d0);
        k_final<<<dim3(2048), dim3(256), 0, stream>>>(
            h2c, domain_id, scale2, shift2, W3c, b3c, (float*)d_out, d0, NC);
    }
}

// Round 2
// 491.730 us; speedup vs baseline: 2.9626x; 2.9626x over previous
//
#include <hip/hip_runtime.h>
#include <hip/hip_bf16.h>

#define B_SZ   8192
#define F_CNT  16
#define E_DIM  32
#define V_CNT  100000
#define D_CNT  8
#define H1     1024
#define H2     512
#define IN_DIM 512
#define EPS_BN 1e-5f

typedef __attribute__((ext_vector_type(8))) unsigned short ushort8;
typedef __attribute__((ext_vector_type(8))) short          frag_ab;
typedef __attribute__((ext_vector_type(4))) float          frag_cd;
typedef __attribute__((ext_vector_type(4))) float          float4v;

__device__ inline unsigned short f2b(float f) {
    unsigned int u = __builtin_bit_cast(unsigned int, f);
    unsigned int r = u + 0x7FFFu + ((u >> 16) & 1u);   // RNE
    return (unsigned short)(r >> 16);
}
__device__ inline float b2f(unsigned short b) {
    return __builtin_bit_cast(float, (unsigned int)b << 16);
}

// async global->LDS DMA, 16B per lane; LDS dest = wave-uniform base + lane*16
__device__ inline void ld_lds16(const unsigned short* g, unsigned short* l) {
    __builtin_amdgcn_global_load_lds(
        (const __attribute__((address_space(1))) unsigned int*)g,
        (__attribute__((address_space(3))) unsigned int*)l, 16, 0, 0);
}

// ---- merged init: W1/W2/W3/b3 fp32->bf16 + zero stats ------------------------
// blocks [0,4096): W1 ; [4096,8192): W2 ; 8192: W3+b3 ; [8193,8217): zero 24576 f
__global__ void k_init(const float* __restrict__ W1, const float* __restrict__ W2,
                       const float* __restrict__ W3, const float* __restrict__ b3,
                       unsigned short* __restrict__ W1c, unsigned short* __restrict__ W2c,
                       unsigned short* __restrict__ W3c, unsigned short* __restrict__ b3c,
                       float* __restrict__ zb) {
    int bid = blockIdx.x, t = threadIdx.x;
    if (bid < 8192) {
        const float* src = (bid < 4096) ? W1 : W2;
        unsigned short* dst = (bid < 4096) ? W1c : W2c;
        long i = ((long)(bid & 4095) * 256 + t) * 4;
        float4v v = *(const float4v*)(src + i);
        dst[i]     = f2b(v[0]);
        dst[i + 1] = f2b(v[1]);
        dst[i + 2] = f2b(v[2]);
        dst[i + 3] = f2b(v[3]);
    } else if (bid == 8192) {
        const float* s = W3 + t * 16;
        unsigned short* d = W3c + t * 16;
#pragma unroll
        for (int j = 0; j < 4; j++) {
            float4v v = *(const float4v*)(s + j * 4);
            d[j * 4 + 0] = f2b(v[0]); d[j * 4 + 1] = f2b(v[1]);
            d[j * 4 + 2] = f2b(v[2]); d[j * 4 + 3] = f2b(v[3]);
        }
        if (t < D_CNT) b3c[t] = f2b(b3[t]);
    } else {
        int i = (bid - 8193) * 1024 + t * 4;
        if (i < 24576) *(float4v*)(zb + i) = (float4v){0.f, 0.f, 0.f, 0.f};
    }
}

// ---- embedding gather fp32 tables -> bf16 emb[b, f*32+e] ---------------------
__global__ void k_gather(const int* __restrict__ feat_ids,
                         const float* __restrict__ tables,
                         unsigned short* __restrict__ emb) {
    int tid = blockIdx.x * 256 + threadIdx.x;    // B*64 threads, 8-elem chunks
    int b = tid >> 6;
    int c = tid & 63;
    int f = c >> 2;
    int id = feat_ids[b * F_CNT + f];
    const float* s = tables + ((long)f * V_CNT + id) * E_DIM + (c & 3) * 8;
    float4v v0 = *(const float4v*)s;
    float4v v1 = *(const float4v*)(s + 4);
    ushort8 o;
#pragma unroll
    for (int i = 0; i < 4; i++) { o[i] = f2b(v0[i]); o[i + 4] = f2b(v1[i]); }
    *(ushort8*)(emb + (long)b * IN_DIM + c * 8) = o;
}

// ---- shared epilogue: bf16 C store + per-column sum/sumsq atomics ------------
// NOTE: no __threadfence here. Round-1 lesson: a per-block device-scope fence
// (L2 writeback/invalidate x512 blocks) cost ~700us. Finalize runs as its own
// tiny dispatch; the kernel boundary is the coherence point.
__device__ inline void gemm_epilogue(frag_cd acc[4][4],
                                     unsigned short* __restrict__ Cd,
                                     float* __restrict__ gsum, float* __restrict__ gsq,
                                     int N, int d, int m0, int n0,
                                     int wm, int wn, int q, int lr, int lane) {
    float s[4], q2[4];
#pragma unroll
    for (int j = 0; j < 4; j++) { s[j] = 0.f; q2[j] = 0.f; }
#pragma unroll
    for (int i = 0; i < 4; i++) {
        int row = m0 + wm + i * 16 + q * 4;          // C/D: col=lane&15, row=quad*4+reg
#pragma unroll
        for (int j = 0; j < 4; j++) {
            int col = n0 + wn + j * 16 + lr;
#pragma unroll
            for (int r = 0; r < 4; r++) {
                float v = acc[i][j][r];
                Cd[(long)(row + r) * N + col] = f2b(v);
                s[j] += v; q2[j] += v * v;
            }
        }
    }
    // collapse the 4 q-quads (same col, different rows): lanes differ in bits 4,5
#pragma unroll
    for (int j = 0; j < 4; j++) {
        s[j]  += __shfl_xor(s[j], 16, 64);  s[j]  += __shfl_xor(s[j], 32, 64);
        q2[j] += __shfl_xor(q2[j], 16, 64); q2[j] += __shfl_xor(q2[j], 32, 64);
    }
    if (lane < 16) {
        float* gs = gsum + (long)d * N + n0 + wn;
        float* gq = gsq  + (long)d * N + n0 + wn;
#pragma unroll
        for (int j = 0; j < 4; j++) {
            atomicAdd(&gs[j * 16 + lane], s[j]);
            atomicAdd(&gq[j * 16 + lane], q2[j]);
        }
    }
}

// ---- Layer-1 GEMM: DMA-staged A (emb) & W; fused BN stats --------------------
__global__ __launch_bounds__(256, 2)
void k_gemm1(const unsigned short* __restrict__ A,
             const unsigned short* __restrict__ W,
             unsigned short* __restrict__ C,
             float* __restrict__ gsum, float* __restrict__ gsq,
             int M, int N, int K, long aBatchStride, int d0) {
    const int z  = blockIdx.z;
    const int m0 = blockIdx.x * 128;
    const int n0 = blockIdx.y * 128;
    const unsigned short* Ad = A + (long)z * aBatchStride;
    const unsigned short* Wd = W + (long)(d0 + z) * N * K;

    __shared__ unsigned short As[128 * 32];   // unpadded: required by global_load_lds
    __shared__ unsigned short Bs[128 * 32];

    const int t    = threadIdx.x;
    const int wave = t >> 6;
    const int lane = t & 63;
    const int wm   = (wave & 1) << 6;
    const int wn   = (wave >> 1) << 6;
    const int q    = lane >> 4;
    const int lr   = lane & 15;

    const int srow = lane >> 2;
    const int scol = (lane & 3) * 8;
    const unsigned short* aG0 = Ad + (long)(m0 + wave * 32 + srow) * K + scol;
    const unsigned short* aG1 = aG0 + 16 * (long)K;
    const unsigned short* wG0 = Wd + (long)(n0 + wave * 32 + srow) * K + scol;
    const unsigned short* wG1 = wG0 + 16 * (long)K;
    unsigned short* aL0 = &As[(wave * 32) * 32];       // wave-uniform
    unsigned short* aL1 = &As[(wave * 32 + 16) * 32];
    unsigned short* wL0 = &Bs[(wave * 32) * 32];
    unsigned short* wL1 = &Bs[(wave * 32 + 16) * 32];

    frag_cd acc[4][4];
#pragma unroll
    for (int i = 0; i < 4; i++)
#pragma unroll
        for (int j = 0; j < 4; j++)
            acc[i][j] = (frag_cd){0.f, 0.f, 0.f, 0.f};

    for (int k0 = 0; k0 < K; k0 += 32) {
        ld_lds16(aG0 + k0, aL0);
        ld_lds16(aG1 + k0, aL1);
        ld_lds16(wG0 + k0, wL0);
        ld_lds16(wG1 + k0, wL1);
        __syncthreads();                       // drains vmcnt before barrier

        frag_ab af[4], bf[4];
#pragma unroll
        for (int i = 0; i < 4; i++) {
            af[i] = *(const frag_ab*)&As[(wm + i * 16 + lr) * 32 + q * 8];
            bf[i] = *(const frag_ab*)&Bs[(wn + i * 16 + lr) * 32 + q * 8];
        }
#pragma unroll
        for (int i = 0; i < 4; i++)
#pragma unroll
            for (int j = 0; j < 4; j++)
                acc[i][j] = __builtin_amdgcn_mfma_f32_16x16x32_bf16(af[i], bf[j], acc[i][j], 0, 0, 0);
        __syncthreads();                       // LDS reads done before next DMA
    }

    unsigned short* Cd = C + (long)z * M * N;
    gemm_epilogue(acc, Cd, gsum, gsq, N, d0 + z, m0, n0, wm, wn, q, lr, lane);
}

// ---- Layer-2 GEMM: reg-staged A with fused BN1(scale/shift)+ReLU; DMA W ------
__global__ __launch_bounds__(256, 2)
void k_gemm2(const unsigned short* __restrict__ A,
             const unsigned short* __restrict__ W,
             unsigned short* __restrict__ C,
             float* __restrict__ gsum, float* __restrict__ gsq,
             const float* __restrict__ sc1, const float* __restrict__ sh1,
             int M, int N, int K, long aBatchStride, int d0) {
    const int z  = blockIdx.z;
    const int m0 = blockIdx.x * 128;
    const int n0 = blockIdx.y * 128;
    const unsigned short* Ad = A + (long)z * aBatchStride;
    const unsigned short* Wd = W + (long)(d0 + z) * N * K;

    __shared__ unsigned short As[128 * 32];
    __shared__ unsigned short Bs[128 * 32];

    const int t    = threadIdx.x;
    const int wave = t >> 6;
    const int lane = t & 63;
    const int wm   = (wave & 1) << 6;
    const int wn   = (wave >> 1) << 6;
    const int q    = lane >> 4;
    const int lr   = lane & 15;

    const int srow = lane >> 2;
    const int scol = (lane & 3) * 8;
    // A reg-staged (BN1+ReLU applied en route); W via global_load_lds
    const unsigned short* aP0 = Ad + (long)(m0 + wave * 32 + srow) * K + scol;
    const unsigned short* aP1 = aP0 + 16 * (long)K;
    const float* scD = sc1 + (long)(d0 + z) * K;   // K == H1; scale/shift index = k
    const float* shD = sh1 + (long)(d0 + z) * K;
    const unsigned short* wG0 = Wd + (long)(n0 + wave * 32 + srow) * K + scol;
    const unsigned short* wG1 = wG0 + 16 * (long)K;
    unsigned short* aL0w = &As[(wave * 32 + srow) * 32 + scol];
    unsigned short* aL1w = aL0w + 16 * 32;
    unsigned short* wL0 = &Bs[(wave * 32) * 32];
    unsigned short* wL1 = &Bs[(wave * 32 + 16) * 32];

    frag_cd acc[4][4];
#pragma unroll
    for (int i = 0; i < 4; i++)
#pragma unroll
        for (int j = 0; j < 4; j++)
            acc[i][j] = (frag_cd){0.f, 0.f, 0.f, 0.f};

    ushort8 x0 = *(const ushort8*)aP0;             // prologue load (k0 = 0)
    ushort8 x1 = *(const ushort8*)aP1;

    for (int k0 = 0; k0 < K; k0 += 32) {
        ld_lds16(wG0 + k0, wL0);                   // W DMA in flight over transform
        ld_lds16(wG1 + k0, wL1);
        float4v sa = *(const float4v*)(scD + k0 + scol);
        float4v sb = *(const float4v*)(scD + k0 + scol + 4);
        float4v ha = *(const float4v*)(shD + k0 + scol);
        float4v hb = *(const float4v*)(shD + k0 + scol + 4);
        ushort8 y0, y1;
#pragma unroll
        for (int i2 = 0; i2 < 8; i2++) {
            float scv = (i2 < 4) ? sa[i2] : sb[i2 - 4];
            float shv = (i2 < 4) ? ha[i2] : hb[i2 - 4];
            y0[i2] = f2b(fmaxf(b2f(x0[i2]) * scv + shv, 0.f));
            y1[i2] = f2b(fmaxf(b2f(x1[i2]) * scv + shv, 0.f));
        }
        *(ushort8*)aL0w = y0;
        *(ushort8*)aL1w = y1;
        __syncthreads();                           // ds_write visible + W DMA drained

        if (k0 + 32 < K) {                         // early-issue next A chunk (T14-lite)
            x0 = *(const ushort8*)(aP0 + k0 + 32);
            x1 = *(const ushort8*)(aP1 + k0 + 32);
        }

        frag_ab af[4], bf[4];
#pragma unroll
        for (int i = 0; i < 4; i++) {
            af[i] = *(const frag_ab*)&As[(wm + i * 16 + lr) * 32 + q * 8];
            bf[i] = *(const frag_ab*)&Bs[(wn + i * 16 + lr) * 32 + q * 8];
        }
#pragma unroll
        for (int i = 0; i < 4; i++)
#pragma unroll
            for (int j = 0; j < 4; j++)
                acc[i][j] = __builtin_amdgcn_mfma_f32_16x16x32_bf16(af[i], bf[j], acc[i][j], 0, 0, 0);
        __syncthreads();
    }

    unsigned short* Cd = C + (long)z * M * N;
    gemm_epilogue(acc, Cd, gsum, gsq, N, d0 + z, m0, n0, wm, wn, q, lr, lane);
}

// ---- stats -> scale/shift (fp32 g/be) ----------------------------------------
__global__ void k_finalize(const float* __restrict__ gsum, const float* __restrict__ gsq,
                           const float* __restrict__ g, const float* __restrict__ be,
                           float* __restrict__ scale, float* __restrict__ shift, int n,
                           int gOff) {
    int i = blockIdx.x * 256 + threadIdx.x;
    if (i >= n) return;
    float mean = gsum[i] * (1.0f / B_SZ);
    float var  = gsq[i] * (1.0f / B_SZ) - mean * mean;
    float sc   = g[gOff + i] * rsqrtf(var + EPS_BN);
    scale[i] = sc;
    shift[i] = be[gOff + i] - mean * sc;
}

// ---- fused BN2+ReLU+W3 dot+sigmoid+domain select (fp32 out) -------------------
__global__ void k_final(const unsigned short* __restrict__ h2c,
                        const int* __restrict__ domain_id,
                        const float* __restrict__ scale2, const float* __restrict__ shift2,
                        const unsigned short* __restrict__ W3, const unsigned short* __restrict__ b3,
                        float* __restrict__ out, int d0, int nc) {
    int wave = threadIdx.x >> 6, lane = threadIdx.x & 63;
    int b = blockIdx.x * 4 + wave;
    int d = domain_id[b];
    if (d < d0 || d >= d0 + nc) return;          // wave-uniform exit
    int o = d * H2 + lane * 8;
    ushort8 v = *(const ushort8*)(h2c + ((long)(d - d0) * B_SZ + b) * H2 + lane * 8);
    ushort8 w = *(const ushort8*)(W3 + o);
    float sum = 0.f;
#pragma unroll
    for (int i = 0; i < 8; i++) {
        float x = b2f(v[i]) * scale2[o + i] + shift2[o + i];
        sum += fmaxf(x, 0.f) * b2f(w[i]);
    }
#pragma unroll
    for (int off = 32; off > 0; off >>= 1) sum += __shfl_xor(sum, off, 64);
    if (lane == 0)
        out[b] = 1.f / (1.f + expf(-(sum + b2f(b3[d]))));
}

__global__ void k_sentinel(float* __restrict__ out, int n) {
    int i = blockIdx.x * 256 + threadIdx.x;
    if (i < n) out[i] = 0.25f;   // diagnostic: ws too small
}

extern "C" void kernel_launch(void* const* d_in, const int* in_sizes, int n_in,
                              void* d_out, int out_size, void* d_ws, size_t ws_size,
                              hipStream_t stream) {
    const int*   feat_ids  = (const int*)d_in[0];
    const int*   domain_id = (const int*)d_in[1];
    const float* tables = (const float*)d_in[2];
    const float* W1  = (const float*)d_in[3];
    // d_in[4] = b1: dead (BN subtracts batch mean)
    const float* g1  = (const float*)d_in[5];
    const float* be1 = (const float*)d_in[6];
    const float* W2  = (const float*)d_in[7];
    // d_in[8] = b2: dead
    const float* g2  = (const float*)d_in[9];
    const float* be2 = (const float*)d_in[10];
    const float* W3  = (const float*)d_in[11];
    const float* b3  = (const float*)d_in[12];

    char* ws = (char*)d_ws;
    float* gsum1  = (float*)ws;            // 8192
    float* gsq1   = gsum1 + 8192;          // 8192
    float* gsum2  = gsq1 + 8192;           // 4096
    float* gsq2   = gsum2 + 4096;          // 4096
    float* scale1 = gsq2 + 4096;           // 8192 (absolute [D][H1])
    float* shift1 = scale1 + 8192;         // 8192
    float* scale2 = shift1 + 8192;         // 4096 (absolute [D][H2])
    float* shift2 = scale2 + 4096;         // 4096
    unsigned short* W1c = (unsigned short*)(ws + (1L  << 20));
    unsigned short* W2c = (unsigned short*)(ws + (9L  << 20));
    unsigned short* W3c = (unsigned short*)(ws + (17L << 20));
    unsigned short* b3c = W3c + D_CNT * H2;
    unsigned short* emb = (unsigned short*)(ws + (18L << 20));

    const long h1Elems = (long)B_SZ * H1;
    const long h2Elems = (long)B_SZ * H2;
    const long perDom  = (h1Elems + h2Elems) * 2;
    const long baseOff = 26L << 20;
    int NC = 0;
    for (int cand = 8; cand >= 1; cand >>= 1)
        if (baseOff + (long)cand * perDom <= (long)ws_size) { NC = cand; break; }
    if (NC == 0) {
        k_sentinel<<<dim3((out_size + 255) / 256), dim3(256), 0, stream>>>(
            (float*)d_out, out_size);
        return;
    }
    unsigned short* h1c = (unsigned short*)(ws + baseOff);
    unsigned short* h2c = h1c + (long)NC * h1Elems;

    // merged: W1/W2/W3/b3 convert + zero(gsum/gsq = 24576 words)
    k_init<<<dim3(8217), dim3(256), 0, stream>>>(W1, W2, W3, b3, W1c, W2c, W3c, b3c, gsum1);
    k_gather<<<dim3(2048), dim3(256), 0, stream>>>(feat_ids, tables, emb);

    for (int d0 = 0; d0 < D_CNT; d0 += NC) {
        // Layer 1: M=8192,N=1024,K=512 ; A=emb shared (stride 0); stats fused
        k_gemm1<<<dim3(64, 8, NC), dim3(256), 0, stream>>>(
            emb, W1c, h1c, gsum1, gsq1, 8192, 1024, 512, 0L, d0);
        k_finalize<<<dim3(NC * 4), dim3(256), 0, stream>>>(
            gsum1 + d0 * H1, gsq1 + d0 * H1, g1, be1,
            scale1 + d0 * H1, shift1 + d0 * H1, NC * H1, d0 * H1);
        // Layer 2: M=8192,N=512,K=1024 ; A=h1c (pre-BN) with fused BN1+ReLU staging
        k_gemm2<<<dim3(64, 4, NC), dim3(256), 0, stream>>>(
            h1c, W2c, h2c, gsum2, gsq2, scale1, shift1, 8192, 512, 1024, h1Elems, d0);
        k_finalize<<<dim3(NC * 2), dim3(256), 0, stream>>>(
            gsum2 + d0 * H2, gsq2 + d0 * H2, g2, be2,
            scale2 + d0 * H2, shift2 + d0 * H2, NC * H2, d0 * H2);
        k_final<<<dim3(2048), dim3(256), 0, stream>>>(
            h2c, domain_id, scale2, shift2, W3c, b3c, (float*)d_out, d0, NC);
    }
}

// Round 3
// 478.499 us; speedup vs baseline: 3.0446x; 1.0277x over previous
//
#include <hip/hip_runtime.h>
#include <hip/hip_bf16.h>

#define B_SZ   8192
#define F_CNT  16
#define E_DIM  32
#define V_CNT  100000
#define D_CNT  8
#define H1     1024
#define H2     512
#define IN_DIM 512
#define EPS_BN 1e-5f

typedef __attribute__((ext_vector_type(8))) unsigned short ushort8;
typedef __attribute__((ext_vector_type(8))) short          frag_ab;
typedef __attribute__((ext_vector_type(4))) float          frag_cd;
typedef __attribute__((ext_vector_type(4))) float          float4v;

__device__ inline unsigned short f2b(float f) {
    unsigned int u = __builtin_bit_cast(unsigned int, f);
    unsigned int r = u + 0x7FFFu + ((u >> 16) & 1u);   // RNE
    return (unsigned short)(r >> 16);
}
__device__ inline float b2f(unsigned short b) {
    return __builtin_bit_cast(float, (unsigned int)b << 16);
}

// async global->LDS DMA, 16B per lane; LDS dest = wave-uniform base + lane*16
__device__ inline void ld_lds16(const unsigned short* g, unsigned short* l) {
    __builtin_amdgcn_global_load_lds(
        (const __attribute__((address_space(1))) unsigned int*)g,
        (__attribute__((address_space(3))) unsigned int*)l, 16, 0, 0);
}

// ---- merged init: W1/W2/W3/b3 fp32->bf16 + zero stats ------------------------
__global__ void k_init(const float* __restrict__ W1, const float* __restrict__ W2,
                       const float* __restrict__ W3, const float* __restrict__ b3,
                       unsigned short* __restrict__ W1c, unsigned short* __restrict__ W2c,
                       unsigned short* __restrict__ W3c, unsigned short* __restrict__ b3c,
                       float* __restrict__ zb) {
    int bid = blockIdx.x, t = threadIdx.x;
    if (bid < 8192) {
        const float* src = (bid < 4096) ? W1 : W2;
        unsigned short* dst = (bid < 4096) ? W1c : W2c;
        long i = ((long)(bid & 4095) * 256 + t) * 4;
        float4v v = *(const float4v*)(src + i);
        dst[i]     = f2b(v[0]);
        dst[i + 1] = f2b(v[1]);
        dst[i + 2] = f2b(v[2]);
        dst[i + 3] = f2b(v[3]);
    } else if (bid == 8192) {
        const float* s = W3 + t * 16;
        unsigned short* d = W3c + t * 16;
#pragma unroll
        for (int j = 0; j < 4; j++) {
            float4v v = *(const float4v*)(s + j * 4);
            d[j * 4 + 0] = f2b(v[0]); d[j * 4 + 1] = f2b(v[1]);
            d[j * 4 + 2] = f2b(v[2]); d[j * 4 + 3] = f2b(v[3]);
        }
        if (t < D_CNT) b3c[t] = f2b(b3[t]);
    } else {
        int i = (bid - 8193) * 1024 + t * 4;
        if (i < 24576) *(float4v*)(zb + i) = (float4v){0.f, 0.f, 0.f, 0.f};
    }
}

// ---- embedding gather fp32 tables -> bf16 emb[b, f*32+e] ---------------------
__global__ void k_gather(const int* __restrict__ feat_ids,
                         const float* __restrict__ tables,
                         unsigned short* __restrict__ emb) {
    int tid = blockIdx.x * 256 + threadIdx.x;    // B*64 threads, 8-elem chunks
    int b = tid >> 6;
    int c = tid & 63;
    int f = c >> 2;
    int id = feat_ids[b * F_CNT + f];
    const float* s = tables + ((long)f * V_CNT + id) * E_DIM + (c & 3) * 8;
    float4v v0 = *(const float4v*)s;
    float4v v1 = *(const float4v*)(s + 4);
    ushort8 o;
#pragma unroll
    for (int i = 0; i < 4; i++) { o[i] = f2b(v0[i]); o[i + 4] = f2b(v1[i]); }
    *(ushort8*)(emb + (long)b * IN_DIM + c * 8) = o;
}

// ---- Layer-1 GEMM: 256x256 tile, BK=64, 8 waves, counted-vmcnt pipeline ------
// LDS layout is K-half-major: [buf][kh][256 rows][32 cols] so phases 0-1 of a
// tile read ONLY plane kh=0 and phases 2-3 only kh=1. Each wave issues 2 DMA
// loads/phase (tile t+1, half kh=ks). At each half boundary exactly 8 own-loads
// are outstanding, oldest 4 = the half about to be read -> s_waitcnt vmcnt(4)
// + barrier (vmcnt retires in order). vmcnt(0) only at the very last half.
// Frag ds_reads cover a permutation of 1024 contiguous bytes (64B rows x16)
// -> bank-conflict-free without swizzle.
__global__ __launch_bounds__(512, 2)
void k_gemm1(const unsigned short* __restrict__ A,
             const unsigned short* __restrict__ W,
             unsigned short* __restrict__ C,
             float* __restrict__ gsum, float* __restrict__ gsq,
             int M, int N, int K, long aBatchStride, int d0) {
    const int z  = blockIdx.z;
    const int m0 = blockIdx.x * 256;
    const int n0 = blockIdx.y * 256;
    const unsigned short* Ad = A + (long)z * aBatchStride;
    const unsigned short* Wd = W + (long)(d0 + z) * (long)N * K;

    __shared__ unsigned short As[2 * 2 * 8192];   // [buf][kh][256][32] bf16 = 64 KiB
    __shared__ unsigned short Bs[2 * 2 * 8192];   // 64 KiB

    const int t    = threadIdx.x;
    const int w    = t >> 6;          // wave 0..7
    const int lane = t & 63;
    const int wr   = w >> 2;          // wave row 0..1 (128 rows each)
    const int wc   = w & 3;           // wave col 0..3 (64 cols each)
    const int q    = lane >> 4;
    const int lr   = lane & 15;

    // staging: slot = sg*8 + w stages 16 rows; lane l -> row l>>2, col (l&3)*8
    const int srow = lane >> 2;
    const int scol = (lane & 3) * 8;
    const unsigned short* aGb[2];
    const unsigned short* wGb[2];
    aGb[0] = Ad + (long)(m0 + w * 16 + srow) * K + scol;
    aGb[1] = aGb[0] + (long)128 * K;
    wGb[0] = Wd + (long)(n0 + w * 16 + srow) * K + scol;
    wGb[1] = wGb[0] + (long)128 * K;

    frag_cd acc[8][4];
#pragma unroll
    for (int i = 0; i < 8; i++)
#pragma unroll
        for (int j = 0; j < 4; j++)
            acc[i][j] = (frag_cd){0.f, 0.f, 0.f, 0.f};

    const int NT = K >> 6;            // K-tiles of 64

    // prologue: stage tile 0 into buf0, H0 first (oldest-4 = H0)
#pragma unroll
    for (int p = 0; p < 4; ++p) {
        const int kh = p >> 1, sg = p & 1;
        ld_lds16(aGb[sg] + kh * 32, &As[kh * 8192 + sg * 4096 + w * 512]);
        ld_lds16(wGb[sg] + kh * 32, &Bs[kh * 8192 + sg * 4096 + w * 512]);
    }

    for (int tt = 0; tt < NT; ++tt) {
        const int b = tt & 1;
        const bool lastT = (tt == NT - 1);
#pragma unroll
        for (int p = 0; p < 4; ++p) {
            const int ks = p >> 1;    // k-slice / LDS plane read this phase
            const int mh = p & 1;     // m-half quadrant + staging slot group
            if (p == 0 || p == 2) {   // half boundary: oldest loads = this plane
                if (p == 2 && lastT)
                    asm volatile("s_waitcnt vmcnt(0)" ::: "memory");
                else
                    asm volatile("s_waitcnt vmcnt(4)" ::: "memory");
                __builtin_amdgcn_s_barrier();
            }
            // register subtile ds-loads (compiler inserts fine-grained lgkm waits)
            frag_ab af[4], bf[4];
            const unsigned short* Ap = &As[b * 16384 + ks * 8192];
            const unsigned short* Bp = &Bs[b * 16384 + ks * 8192];
#pragma unroll
            for (int i = 0; i < 4; ++i) {
                af[i] = *(const frag_ab*)&Ap[(wr * 128 + (mh * 4 + i) * 16 + lr) * 32 + q * 8];
                bf[i] = *(const frag_ab*)&Bp[(wc * 64 + i * 16 + lr) * 32 + q * 8];
            }
            // prefetch tile t+1 (half kh=ks, slot group mh) into buf b^1
            if (!lastT) {
                const long ko = (long)(tt + 1) * 64 + ks * 32;
                ld_lds16(aGb[mh] + ko, &As[(b ^ 1) * 16384 + ks * 8192 + mh * 4096 + w * 512]);
                ld_lds16(wGb[mh] + ko, &Bs[(b ^ 1) * 16384 + ks * 8192 + mh * 4096 + w * 512]);
            }
            __builtin_amdgcn_s_barrier();
            asm volatile("s_waitcnt lgkmcnt(0)" ::: "memory");
            __builtin_amdgcn_sched_barrier(0);   // rule 18: pin MFMA after the wait
            __builtin_amdgcn_s_setprio(1);
#pragma unroll
            for (int i = 0; i < 4; ++i)
#pragma unroll
                for (int j = 0; j < 4; ++j)
                    acc[mh * 4 + i][j] = __builtin_amdgcn_mfma_f32_16x16x32_bf16(
                        af[i], bf[j], acc[mh * 4 + i][j], 0, 0, 0);
            __builtin_amdgcn_s_setprio(0);
            __builtin_amdgcn_s_barrier();
        }
    }

    // epilogue: bf16 C store + per-column sum/sumsq atomics (no fence; round-1 lesson)
    unsigned short* Cd = C + (long)z * (long)M * N;
    float s[4], q2[4];
#pragma unroll
    for (int j = 0; j < 4; j++) { s[j] = 0.f; q2[j] = 0.f; }
#pragma unroll
    for (int I = 0; I < 8; ++I) {
        int row = m0 + wr * 128 + I * 16 + q * 4;   // C/D: col=lane&15, row=quad*4+reg
#pragma unroll
        for (int j = 0; j < 4; ++j) {
            int col = n0 + wc * 64 + j * 16 + lr;
#pragma unroll
            for (int r = 0; r < 4; ++r) {
                float v = acc[I][j][r];
                Cd[(long)(row + r) * N + col] = f2b(v);
                s[j] += v; q2[j] += v * v;
            }
        }
    }
#pragma unroll
    for (int j = 0; j < 4; j++) {
        s[j]  += __shfl_xor(s[j], 16, 64);  s[j]  += __shfl_xor(s[j], 32, 64);
        q2[j] += __shfl_xor(q2[j], 16, 64); q2[j] += __shfl_xor(q2[j], 32, 64);
    }
    if (lane < 16) {
        float* gs = gsum + (long)(d0 + z) * N + n0 + wc * 64;
        float* gq = gsq  + (long)(d0 + z) * N + n0 + wc * 64;
#pragma unroll
        for (int j = 0; j < 4; j++) {
            atomicAdd(&gs[j * 16 + lane], s[j]);
            atomicAdd(&gq[j * 16 + lane], q2[j]);
        }
    }
}

// ---- shared epilogue for 128-tile gemm2 --------------------------------------
__device__ inline void gemm_epilogue(frag_cd acc[4][4],
                                     unsigned short* __restrict__ Cd,
                                     float* __restrict__ gsum, float* __restrict__ gsq,
                                     int N, int d, int m0, int n0,
                                     int wm, int wn, int q, int lr, int lane) {
    float s[4], q2[4];
#pragma unroll
    for (int j = 0; j < 4; j++) { s[j] = 0.f; q2[j] = 0.f; }
#pragma unroll
    for (int i = 0; i < 4; i++) {
        int row = m0 + wm + i * 16 + q * 4;
#pragma unroll
        for (int j = 0; j < 4; j++) {
            int col = n0 + wn + j * 16 + lr;
#pragma unroll
            for (int r = 0; r < 4; r++) {
                float v = acc[i][j][r];
                Cd[(long)(row + r) * N + col] = f2b(v);
                s[j] += v; q2[j] += v * v;
            }
        }
    }
#pragma unroll
    for (int j = 0; j < 4; j++) {
        s[j]  += __shfl_xor(s[j], 16, 64);  s[j]  += __shfl_xor(s[j], 32, 64);
        q2[j] += __shfl_xor(q2[j], 16, 64); q2[j] += __shfl_xor(q2[j], 32, 64);
    }
    if (lane < 16) {
        float* gs = gsum + (long)d * N + n0 + wn;
        float* gq = gsq  + (long)d * N + n0 + wn;
#pragma unroll
        for (int j = 0; j < 4; j++) {
            atomicAdd(&gs[j * 16 + lane], s[j]);
            atomicAdd(&gq[j * 16 + lane], q2[j]);
        }
    }
}

// ---- Layer-2 GEMM: reg-staged A with fused BN1(scale/shift)+ReLU; DMA W ------
__global__ __launch_bounds__(256, 2)
void k_gemm2(const unsigned short* __restrict__ A,
             const unsigned short* __restrict__ W,
             unsigned short* __restrict__ C,
             float* __restrict__ gsum, float* __restrict__ gsq,
             const float* __restrict__ sc1, const float* __restrict__ sh1,
             int M, int N, int K, long aBatchStride, int d0) {
    const int z  = blockIdx.z;
    const int m0 = blockIdx.x * 128;
    const int n0 = blockIdx.y * 128;
    const unsigned short* Ad = A + (long)z * aBatchStride;
    const unsigned short* Wd = W + (long)(d0 + z) * N * K;

    __shared__ unsigned short As[128 * 32];
    __shared__ unsigned short Bs[128 * 32];

    const int t    = threadIdx.x;
    const int wave = t >> 6;
    const int lane = t & 63;
    const int wm   = (wave & 1) << 6;
    const int wn   = (wave >> 1) << 6;
    const int q    = lane >> 4;
    const int lr   = lane & 15;

    const int srow = lane >> 2;
    const int scol = (lane & 3) * 8;
    const unsigned short* aP0 = Ad + (long)(m0 + wave * 32 + srow) * K + scol;
    const unsigned short* aP1 = aP0 + 16 * (long)K;
    const float* scD = sc1 + (long)(d0 + z) * K;
    const float* shD = sh1 + (long)(d0 + z) * K;
    const unsigned short* wG0 = Wd + (long)(n0 + wave * 32 + srow) * K + scol;
    const unsigned short* wG1 = wG0 + 16 * (long)K;
    unsigned short* aL0w = &As[(wave * 32 + srow) * 32 + scol];
    unsigned short* aL1w = aL0w + 16 * 32;
    unsigned short* wL0 = &Bs[(wave * 32) * 32];
    unsigned short* wL1 = &Bs[(wave * 32 + 16) * 32];

    frag_cd acc[4][4];
#pragma unroll
    for (int i = 0; i < 4; i++)
#pragma unroll
        for (int j = 0; j < 4; j++)
            acc[i][j] = (frag_cd){0.f, 0.f, 0.f, 0.f};

    ushort8 x0 = *(const ushort8*)aP0;
    ushort8 x1 = *(const ushort8*)aP1;

    for (int k0 = 0; k0 < K; k0 += 32) {
        ld_lds16(wG0 + k0, wL0);
        ld_lds16(wG1 + k0, wL1);
        float4v sa = *(const float4v*)(scD + k0 + scol);
        float4v sb = *(const float4v*)(scD + k0 + scol + 4);
        float4v ha = *(const float4v*)(shD + k0 + scol);
        float4v hb = *(const float4v*)(shD + k0 + scol + 4);
        ushort8 y0, y1;
#pragma unroll
        for (int i2 = 0; i2 < 8; i2++) {
            float scv = (i2 < 4) ? sa[i2] : sb[i2 - 4];
            float shv = (i2 < 4) ? ha[i2] : hb[i2 - 4];
            y0[i2] = f2b(fmaxf(b2f(x0[i2]) * scv + shv, 0.f));
            y1[i2] = f2b(fmaxf(b2f(x1[i2]) * scv + shv, 0.f));
        }
        *(ushort8*)aL0w = y0;
        *(ushort8*)aL1w = y1;
        __syncthreads();

        if (k0 + 32 < K) {
            x0 = *(const ushort8*)(aP0 + k0 + 32);
            x1 = *(const ushort8*)(aP1 + k0 + 32);
        }

        frag_ab af[4], bf[4];
#pragma unroll
        for (int i = 0; i < 4; i++) {
            af[i] = *(const frag_ab*)&As[(wm + i * 16 + lr) * 32 + q * 8];
            bf[i] = *(const frag_ab*)&Bs[(wn + i * 16 + lr) * 32 + q * 8];
        }
#pragma unroll
        for (int i = 0; i < 4; i++)
#pragma unroll
            for (int j = 0; j < 4; j++)
                acc[i][j] = __builtin_amdgcn_mfma_f32_16x16x32_bf16(af[i], bf[j], acc[i][j], 0, 0, 0);
        __syncthreads();
    }

    unsigned short* Cd = C + (long)z * M * N;
    gemm_epilogue(acc, Cd, gsum, gsq, N, d0 + z, m0, n0, wm, wn, q, lr, lane);
}

// ---- stats -> scale/shift (fp32 g/be) ----------------------------------------
__global__ void k_finalize(const float* __restrict__ gsum, const float* __restrict__ gsq,
                           const float* __restrict__ g, const float* __restrict__ be,
                           float* __restrict__ scale, float* __restrict__ shift, int n,
                           int gOff) {
    int i = blockIdx.x * 256 + threadIdx.x;
    if (i >= n) return;
    float mean = gsum[i] * (1.0f / B_SZ);
    float var  = gsq[i] * (1.0f / B_SZ) - mean * mean;
    float sc   = g[gOff + i] * rsqrtf(var + EPS_BN);
    scale[i] = sc;
    shift[i] = be[gOff + i] - mean * sc;
}

// ---- fused BN2+ReLU+W3 dot+sigmoid+domain select (fp32 out) -------------------
__global__ void k_final(const unsigned short* __restrict__ h2c,
                        const int* __restrict__ domain_id,
                        const float* __restrict__ scale2, const float* __restrict__ shift2,
                        const unsigned short* __restrict__ W3, const unsigned short* __restrict__ b3,
                        float* __restrict__ out, int d0, int nc) {
    int wave = threadIdx.x >> 6, lane = threadIdx.x & 63;
    int b = blockIdx.x * 4 + wave;
    int d = domain_id[b];
    if (d < d0 || d >= d0 + nc) return;
    int o = d * H2 + lane * 8;
    ushort8 v = *(const ushort8*)(h2c + ((long)(d - d0) * B_SZ + b) * H2 + lane * 8);
    ushort8 w = *(const ushort8*)(W3 + o);
    float sum = 0.f;
#pragma unroll
    for (int i = 0; i < 8; i++) {
        float x = b2f(v[i]) * scale2[o + i] + shift2[o + i];
        sum += fmaxf(x, 0.f) * b2f(w[i]);
    }
#pragma unroll
    for (int off = 32; off > 0; off >>= 1) sum += __shfl_xor(sum, off, 64);
    if (lane == 0)
        out[b] = 1.f / (1.f + expf(-(sum + b2f(b3[d]))));
}

__global__ void k_sentinel(float* __restrict__ out, int n) {
    int i = blockIdx.x * 256 + threadIdx.x;
    if (i < n) out[i] = 0.25f;
}

extern "C" void kernel_launch(void* const* d_in, const int* in_sizes, int n_in,
                              void* d_out, int out_size, void* d_ws, size_t ws_size,
                              hipStream_t stream) {
    const int*   feat_ids  = (const int*)d_in[0];
    const int*   domain_id = (const int*)d_in[1];
    const float* tables = (const float*)d_in[2];
    const float* W1  = (const float*)d_in[3];
    const float* g1  = (const float*)d_in[5];
    const float* be1 = (const float*)d_in[6];
    const float* W2  = (const float*)d_in[7];
    const float* g2  = (const float*)d_in[9];
    const float* be2 = (const float*)d_in[10];
    const float* W3  = (const float*)d_in[11];
    const float* b3  = (const float*)d_in[12];

    char* ws = (char*)d_ws;
    float* gsum1  = (float*)ws;            // 8192
    float* gsq1   = gsum1 + 8192;          // 8192
    float* gsum2  = gsq1 + 8192;           // 4096
    float* gsq2   = gsum2 + 4096;          // 4096
    float* scale1 = gsq2 + 4096;           // 8192 (absolute [D][H1])
    float* shift1 = scale1 + 8192;         // 8192
    float* scale2 = shift1 + 8192;         // 4096 (absolute [D][H2])
    float* shift2 = scale2 + 4096;         // 4096
    unsigned short* W1c = (unsigned short*)(ws + (1L  << 20));
    unsigned short* W2c = (unsigned short*)(ws + (9L  << 20));
    unsigned short* W3c = (unsigned short*)(ws + (17L << 20));
    unsigned short* b3c = W3c + D_CNT * H2;
    unsigned short* emb = (unsigned short*)(ws + (18L << 20));

    const long h1Elems = (long)B_SZ * H1;
    const long h2Elems = (long)B_SZ * H2;
    const long perDom  = (h1Elems + h2Elems) * 2;
    const long baseOff = 26L << 20;
    int NC = 0;
    for (int cand = 8; cand >= 1; cand >>= 1)
        if (baseOff + (long)cand * perDom <= (long)ws_size) { NC = cand; break; }
    if (NC == 0) {
        k_sentinel<<<dim3((out_size + 255) / 256), dim3(256), 0, stream>>>(
            (float*)d_out, out_size);
        return;
    }
    unsigned short* h1c = (unsigned short*)(ws + baseOff);
    unsigned short* h2c = h1c + (long)NC * h1Elems;

    k_init<<<dim3(8217), dim3(256), 0, stream>>>(W1, W2, W3, b3, W1c, W2c, W3c, b3c, gsum1);
    k_gather<<<dim3(2048), dim3(256), 0, stream>>>(feat_ids, tables, emb);

    for (int d0 = 0; d0 < D_CNT; d0 += NC) {
        // Layer 1: M=8192,N=1024,K=512 ; 256x256 pipelined tile; stats fused
        k_gemm1<<<dim3(32, 4, NC), dim3(512), 0, stream>>>(
            emb, W1c, h1c, gsum1, gsq1, 8192, 1024, 512, 0L, d0);
        k_finalize<<<dim3(NC * 4), dim3(256), 0, stream>>>(
            gsum1 + d0 * H1, gsq1 + d0 * H1, g1, be1,
            scale1 + d0 * H1, shift1 + d0 * H1, NC * H1, d0 * H1);
        // Layer 2: M=8192,N=512,K=1024 ; A=h1c (pre-BN) with fused BN1+ReLU staging
        k_gemm2<<<dim3(64, 4, NC), dim3(256), 0, stream>>>(
            h1c, W2c, h2c, gsum2, gsq2, scale1, shift1, 8192, 512, 1024, h1Elems, d0);
        k_finalize<<<dim3(NC * 2), dim3(256), 0, stream>>>(
            gsum2 + d0 * H2, gsq2 + d0 * H2, g2, be2,
            scale2 + d0 * H2, shift2 + d0 * H2, NC * H2, d0 * H2);
        k_final<<<dim3(2048), dim3(256), 0, stream>>>(
            h2c, domain_id, scale2, shift2, W3c, b3c, (float*)d_out, d0, NC);
    }
}